// Round 1
// baseline (79.239 us; speedup 1.0000x reference)
//
#include <hip/hip_runtime.h>

#define KOBJ 128
#define QMIN 0.5f
#define SB   1.0f

// ---- workspace layout (bytes) ----
// 0      : unsigned long long key[8*128]   (8192 B)   packed (beta_bits<<32)|(~n)
// 8192   : float xax[8*128]                (4096 B)
// 12288  : float xay[8*128]                (4096 B)
// 16384  : float qa [8*128]                (4096 B)   q_alpha * present
// 20480  : float pair[8]
// 20512  : float lbeta[8]                  (already divided by n_obj)
// 20544  : float nsum[8]
// 20576  : uint  ncnt[8]
// total used: 20608 B (init by one hipMemsetAsync to 0)

__global__ void oc_scan(const float* __restrict__ beta,
                        const int* __restrict__ t_idx,
                        unsigned long long* __restrict__ key,
                        float* __restrict__ nsum,
                        unsigned int* __restrict__ ncnt,
                        int N) {
    const int b = blockIdx.y;
    const int n = blockIdx.x * blockDim.x + threadIdx.x;
    float bc = 0.f;
    int t = -1;
    const bool valid = (n < N);
    if (valid) {
        bc = fminf(fmaxf(beta[b * N + n], 1e-6f), 1.0f - 1e-5f);
        t = t_idx[b * N + n];
        unsigned long long k =
            ((unsigned long long)__float_as_uint(bc) << 32) |
            (unsigned long long)(0xFFFFFFFFu - (unsigned int)n);
        atomicMax(&key[b * KOBJ + t], k);
    }
    // block-reduce noise sum / count (one atomic each per block)
    float ns = (valid && t == 0) ? bc : 0.f;
    unsigned int nc = (valid && t == 0) ? 1u : 0u;
    #pragma unroll
    for (int off = 32; off; off >>= 1) {
        ns += __shfl_down(ns, off, 64);
        nc += __shfl_down(nc, off, 64);
    }
    __shared__ float s_ns[4];
    __shared__ unsigned int s_nc[4];
    const int lane = threadIdx.x & 63, wv = threadIdx.x >> 6;
    if (lane == 0) { s_ns[wv] = ns; s_nc[wv] = nc; }
    __syncthreads();
    if (threadIdx.x == 0) {
        float a = 0.f; unsigned int c = 0u;
        const int nw = (int)(blockDim.x >> 6);
        for (int w = 0; w < nw; ++w) { a += s_ns[w]; c += s_nc[w]; }
        if (a != 0.f) atomicAdd(&nsum[b], a);
        if (c)        atomicAdd(&ncnt[b], c);
    }
}

__global__ void oc_gather(const float* __restrict__ cc,
                          const unsigned long long* __restrict__ key,
                          float* __restrict__ xax,
                          float* __restrict__ xay,
                          float* __restrict__ qa,
                          float* __restrict__ lbeta,
                          int N) {
    const int b = blockIdx.x;
    const int k = threadIdx.x;   // 128 threads
    const unsigned long long kv = key[b * KOBJ + k];
    const bool seen = (kv != 0ull);
    const bool present = seen && (k > 0);
    float x = 0.f, y = 0.f, qv = 0.f, lb = 0.f;
    if (seen) {
        const unsigned int na = 0xFFFFFFFFu - (unsigned int)(kv & 0xFFFFFFFFull);
        const float ba = __uint_as_float((unsigned int)(kv >> 32));
        x = cc[((size_t)b * N + na) * 2 + 0];
        y = cc[((size_t)b * N + na) * 2 + 1];
        const float a = atanhf(ba / 1.002f);
        qv = a * a + QMIN;
        if (present) lb = 1.f - ba;
    }
    xax[b * KOBJ + k] = x;
    xay[b * KOBJ + k] = y;
    qa [b * KOBJ + k] = present ? qv : 0.f;

    unsigned int pc = present ? 1u : 0u;
    #pragma unroll
    for (int off = 32; off; off >>= 1) {
        lb += __shfl_down(lb, off, 64);
        pc += __shfl_down(pc, off, 64);
    }
    __shared__ float s_lb[2];
    __shared__ unsigned int s_pc[2];
    const int lane = threadIdx.x & 63, wv = threadIdx.x >> 6;
    if (lane == 0) { s_lb[wv] = lb; s_pc[wv] = pc; }
    __syncthreads();
    if (threadIdx.x == 0) {
        const float lbt = s_lb[0] + s_lb[1];
        const unsigned int nobj = s_pc[0] + s_pc[1];
        lbeta[b] = lbt / (float)max(nobj, 1u);
    }
}

__global__ void oc_pairs(const float* __restrict__ cc,
                         const float* __restrict__ beta,
                         const int* __restrict__ t_idx,
                         const float* __restrict__ xax,
                         const float* __restrict__ xay,
                         const float* __restrict__ qa,
                         float* __restrict__ pair,
                         int N) {
    __shared__ float sx[KOBJ], sy[KOBJ], sq[KOBJ];
    const int b = blockIdx.y;
    const int n = blockIdx.x * blockDim.x + threadIdx.x;
    if (threadIdx.x < KOBJ) {
        sx[threadIdx.x] = xax[b * KOBJ + threadIdx.x];
        sy[threadIdx.x] = xay[b * KOBJ + threadIdx.x];
        sq[threadIdx.x] = qa [b * KOBJ + threadIdx.x];
    }
    __syncthreads();

    float x = 0.f, y = 0.f, qn = 0.f;
    int t = -1;
    if (n < N) {
        x = cc[((size_t)b * N + n) * 2 + 0];
        y = cc[((size_t)b * N + n) * 2 + 1];
        const float bc = fminf(fmaxf(beta[b * N + n], 1e-6f), 1.0f - 1e-5f);
        const float a = atanhf(bc / 1.002f);
        qn = a * a + QMIN;
        t = t_idx[b * N + n];
    }
    float acc = 0.f;
    #pragma unroll 8
    for (int k = 0; k < KOBJ; ++k) {
        const float dx = x - sx[k];
        const float dy = y - sy[k];
        const float d2 = dx * dx + dy * dy;
        const float d = sqrtf(d2 + 1e-6f);
        const float val = (k == t) ? d2 : fmaxf(0.f, 1.f - d);
        acc += val * sq[k];
    }
    acc *= qn;  // multiply own q once

    #pragma unroll
    for (int off = 32; off; off >>= 1) acc += __shfl_down(acc, off, 64);
    __shared__ float s_acc[4];
    if ((threadIdx.x & 63) == 0) s_acc[threadIdx.x >> 6] = acc;
    __syncthreads();
    if (threadIdx.x == 0) {
        atomicAdd(&pair[b], s_acc[0] + s_acc[1] + s_acc[2] + s_acc[3]);
    }
}

__global__ void oc_final(const float* __restrict__ pair,
                         const float* __restrict__ lbeta,
                         const float* __restrict__ nsum,
                         const unsigned int* __restrict__ ncnt,
                         float* __restrict__ out,
                         int N, int B) {
    if (threadIdx.x == 0) {
        float loss = 0.f;
        for (int b = 0; b < B; ++b) {
            const float ln = SB * nsum[b] / (float)max(ncnt[b], 1u);
            loss += pair[b] / (float)N + lbeta[b] + ln;
        }
        out[0] = loss / (float)B;
    }
}

extern "C" void kernel_launch(void* const* d_in, const int* in_sizes, int n_in,
                              void* d_out, int out_size, void* d_ws, size_t ws_size,
                              hipStream_t stream) {
    const float* cc   = (const float*)d_in[0];   // (B,N,2) f32
    const float* beta = (const float*)d_in[1];   // (B,N)   f32
    const int*   tid  = (const int*)d_in[2];     // (B,N)   i32
    float* out = (float*)d_out;

    const int B = 8;
    const int N = in_sizes[1] / B;

    char* ws = (char*)d_ws;
    unsigned long long* key = (unsigned long long*)(ws + 0);
    float* xax   = (float*)(ws + 8192);
    float* xay   = (float*)(ws + 12288);
    float* qa    = (float*)(ws + 16384);
    float* pair  = (float*)(ws + 20480);
    float* lbeta = (float*)(ws + 20512);
    float* nsum  = (float*)(ws + 20544);
    unsigned int* ncnt = (unsigned int*)(ws + 20576);

    hipMemsetAsync(d_ws, 0, 20608, stream);

    const int BS = 256;
    dim3 gridScan((N + BS - 1) / BS, B);
    oc_scan<<<gridScan, BS, 0, stream>>>(beta, tid, key, nsum, ncnt, N);
    oc_gather<<<dim3(B), KOBJ, 0, stream>>>(cc, key, xax, xay, qa, lbeta, N);
    oc_pairs<<<gridScan, BS, 0, stream>>>(cc, beta, tid, xax, xay, qa, pair, N);
    oc_final<<<dim3(1), 64, 0, stream>>>(pair, lbeta, nsum, ncnt, out, N, B);
}

// Round 3
// 62.248 us; speedup vs baseline: 1.2730x; 1.2730x over previous
//
#include <hip/hip_runtime.h>

#define KOBJ  128
#define QMIN  0.5f
#define SB    1.0f
#define BDIM  256
#define NBPB  40            // scan/pairs blocks per batch element
#define BATCH 8
#define NBLK  (NBPB * BATCH)

// ---- workspace layout (bytes); NO zero-init required (plain stores only) ----
// 0      : u64  pkey [NBLK][KOBJ]  327680 B  per-block argmax partial keys
// 327680 : f32  nsp  [NBLK]          1280 B  per-block noise-beta partial sum
// 328960 : u32  ncp  [NBLK]          1280 B  per-block noise count partial
// 330240 : f32  pairp[NBLK]          1280 B  per-block pair-potential partial
// total 331520 B

__device__ __forceinline__ float waveRedF(float v) {
    #pragma unroll
    for (int o = 32; o; o >>= 1) v += __shfl_down(v, o, 64);
    return v;
}
__device__ __forceinline__ unsigned int waveRedU(unsigned int v) {
    #pragma unroll
    for (int o = 32; o; o >>= 1) v += __shfl_down(v, o, 64);
    return v;
}

__global__ void __launch_bounds__(BDIM)
oc_scan(const float* __restrict__ beta, const int* __restrict__ t_idx,
        unsigned long long* __restrict__ pkey,
        float* __restrict__ nsp, unsigned int* __restrict__ ncp, int N) {
    const int tid = threadIdx.x;
    const int b   = blockIdx.y;
    const int sub = blockIdx.x;
    const int bid = b * NBPB + sub;
    const int chunk = (N + NBPB - 1) / NBPB;
    const int n0 = sub * chunk;
    const int n1 = min(n0 + chunk, N);

    __shared__ unsigned long long skey[KOBJ];
    if (tid < KOBJ) skey[tid] = 0ull;
    __syncthreads();

    float ns = 0.f;
    unsigned int nc = 0u;
    for (int n = n0 + tid; n < n1; n += BDIM) {
        const float bc = fminf(fmaxf(beta[(size_t)b * N + n], 1e-6f), 1.0f - 1e-5f);
        const int t = t_idx[(size_t)b * N + n];
        const unsigned long long kk =
            ((unsigned long long)__float_as_uint(bc) << 32) |
            (unsigned long long)(~(unsigned int)n);          // ties -> smallest n
        atomicMax(&skey[t], kk);                              // LDS atomic
        if (t == 0) { ns += bc; nc++; }
    }
    __syncthreads();
    if (tid < KOBJ) pkey[(size_t)bid * KOBJ + tid] = skey[tid];

    ns = waveRedF(ns);
    nc = waveRedU(nc);
    __shared__ float s_ns[4];
    __shared__ unsigned int s_nc[4];
    if ((tid & 63) == 0) { s_ns[tid >> 6] = ns; s_nc[tid >> 6] = nc; }
    __syncthreads();
    if (tid == 0) {
        float a = 0.f; unsigned int c = 0u;
        #pragma unroll
        for (int w = 0; w < BDIM / 64; ++w) { a += s_ns[w]; c += s_nc[w]; }
        nsp[bid] = a; ncp[bid] = c;
    }
}

__global__ void __launch_bounds__(BDIM)
oc_pairs(const float* __restrict__ cc, const float* __restrict__ beta,
         const int* __restrict__ t_idx,
         const unsigned long long* __restrict__ pkey,
         float* __restrict__ pairp, int N) {
    const int tid = threadIdx.x;
    const int b   = blockIdx.y;
    const int sub = blockIdx.x;
    const int bid = b * NBPB + sub;
    const int chunk = (N + NBPB - 1) / NBPB;
    const int n0 = sub * chunk;
    const int n1 = min(n0 + chunk, N);

    __shared__ float2 sxy[KOBJ];
    __shared__ float  sqv[KOBJ];

    // build alpha table in-block from the 40 per-block partials (L2-resident)
    if (tid < KOBJ) {
        unsigned long long kv = 0ull;
        #pragma unroll 8
        for (int s = 0; s < NBPB; ++s) {
            const unsigned long long v = pkey[(size_t)(b * NBPB + s) * KOBJ + tid];
            kv = v > kv ? v : kv;
        }
        float x = 0.f, y = 0.f, qv = 0.f;
        const bool present = (kv != 0ull) && (tid > 0);
        if (kv != 0ull) {
            const unsigned int na = ~(unsigned int)(kv & 0xFFFFFFFFull);
            const float ba = __uint_as_float((unsigned int)(kv >> 32));
            const float2 xy = *(const float2*)&cc[((size_t)b * N + na) * 2];
            x = xy.x; y = xy.y;
            const float a = atanhf(ba / 1.002f);
            qv = a * a + QMIN;
        }
        sxy[tid] = make_float2(x, y);
        sqv[tid] = present ? qv : 0.f;
    }
    __syncthreads();

    float acc_tot = 0.f;
    for (int n = n0 + tid; n < n1; n += BDIM) {
        const float2 xy = *(const float2*)&cc[((size_t)b * N + n) * 2];
        const float bc = fminf(fmaxf(beta[(size_t)b * N + n], 1e-6f), 1.0f - 1e-5f);
        const int t = t_idx[(size_t)b * N + n];
        const float a = atanhf(bc / 1.002f);
        const float qn = a * a + QMIN;
        float acc = 0.f;
        #pragma unroll 8
        for (int k = 0; k < KOBJ; ++k) {
            const float dx = xy.x - sxy[k].x;
            const float dy = xy.y - sxy[k].y;
            const float d2 = fmaf(dy, dy, dx * dx);
            const float d = sqrtf(d2 + 1e-6f);
            acc = fmaf(fmaxf(0.f, 1.f - d), sqv[k], acc);    // repulsive for ALL k
        }
        // patch k==t: attractive d2 replaces the repulsive term
        const float2 st = sxy[t];
        const float dxt = xy.x - st.x;
        const float dyt = xy.y - st.y;
        const float d2t = fmaf(dyt, dyt, dxt * dxt);
        const float dt = sqrtf(d2t + 1e-6f);
        acc += sqv[t] * (d2t - fmaxf(0.f, 1.f - dt));
        acc_tot += acc * qn;
    }

    acc_tot = waveRedF(acc_tot);
    __shared__ float s_acc[4];
    if ((tid & 63) == 0) s_acc[tid >> 6] = acc_tot;
    __syncthreads();
    if (tid == 0) {
        float s = 0.f;
        #pragma unroll
        for (int w = 0; w < BDIM / 64; ++w) s += s_acc[w];
        pairp[bid] = s;
    }
}

__global__ void __launch_bounds__(512)
oc_final(const unsigned long long* __restrict__ pkey,
         const float* __restrict__ nsp, const unsigned int* __restrict__ ncp,
         const float* __restrict__ pairp, float* __restrict__ out, int N) {
    const int tid = threadIdx.x;
    const int wv = tid >> 6;       // wave id == batch id (8 waves)
    const int lane = tid & 63;
    __shared__ float s_terms[8];
    __shared__ float s_p[8];

    // per-wave: L_beta + L_noise for batch b = wv
    float lb = 0.f; unsigned int pc = 0u;
    for (int k = lane; k < KOBJ; k += 64) {
        unsigned long long kv = 0ull;
        for (int s = 0; s < NBPB; ++s) {
            const unsigned long long v = pkey[(size_t)(wv * NBPB + s) * KOBJ + k];
            kv = v > kv ? v : kv;
        }
        if (kv != 0ull && k > 0) {
            const float ba = __uint_as_float((unsigned int)(kv >> 32));
            lb += 1.f - ba;
            pc++;
        }
    }
    lb = waveRedF(lb);
    pc = waveRedU(pc);

    float ns = 0.f; unsigned int nc = 0u;
    for (int s = lane; s < NBPB; s += 64) {
        ns += nsp[wv * NBPB + s];
        nc += ncp[wv * NBPB + s];
    }
    ns = waveRedF(ns);
    nc = waveRedU(nc);
    if (lane == 0)
        s_terms[wv] = lb / (float)max(pc, 1u) + SB * ns / (float)max(nc, 1u);

    // pair-partials sum (all 512 threads)
    float p = 0.f;
    for (int i = tid; i < NBLK; i += 512) p += pairp[i];
    p = waveRedF(p);
    if (lane == 0) s_p[wv] = p;
    __syncthreads();
    if (tid == 0) {
        float P = 0.f, L = 0.f;
        #pragma unroll
        for (int w = 0; w < 8; ++w) { P += s_p[w]; L += s_terms[w]; }
        out[0] = (P / (float)N + L) / (float)BATCH;
    }
}

extern "C" void kernel_launch(void* const* d_in, const int* in_sizes, int n_in,
                              void* d_out, int out_size, void* d_ws, size_t ws_size,
                              hipStream_t stream) {
    const float* cc   = (const float*)d_in[0];   // (B,N,2) f32
    const float* beta = (const float*)d_in[1];   // (B,N)   f32
    const int*   tid  = (const int*)d_in[2];     // (B,N)   i32
    float* out = (float*)d_out;
    const int N = in_sizes[1] / BATCH;

    char* ws = (char*)d_ws;
    unsigned long long* pkey = (unsigned long long*)(ws + 0);
    float*        nsp   = (float*)(ws + 327680);
    unsigned int* ncp   = (unsigned int*)(ws + 328960);
    float*        pairp = (float*)(ws + 330240);

    dim3 grid(NBPB, BATCH);
    oc_scan <<<grid, BDIM, 0, stream>>>(beta, tid, pkey, nsp, ncp, N);
    oc_pairs<<<grid, BDIM, 0, stream>>>(cc, beta, tid, pkey, pairp, N);
    oc_final<<<dim3(1), 512, 0, stream>>>(pkey, nsp, ncp, pairp, out, N);
}

// Round 4
// 43.416 us; speedup vs baseline: 1.8251x; 1.4338x over previous
//
#include <hip/hip_runtime.h>

#define KOBJ  128
#define QMIN  0.5f
#define SB    1.0f
#define BDIM  256
#define NSCB  128           // scan blocks per batch element
#define BATCH 8
#define PPB   256           // points per pairs-block (1 per thread)

// ---- workspace layout (bytes); NO zero-init required (plain stores only) ----
// 0       : u64  pkey [BATCH*NSCB][KOBJ]  1048576 B  per-block argmax partial keys
// 1048576 : f32  nsp  [BATCH*NSCB]           4096 B  per-block noise-beta partials
// 1052672 : u32  ncp  [BATCH*NSCB]           4096 B  per-block noise count partials
// 1056768 : f4   xaq  [BATCH][KOBJ]         16384 B  {x_a, y_a, q_a*present, 0}
// 1073152 : f32  terms[BATCH]                  32 B  L_beta + L_noise per batch
// 1073184 : f32  pairp[BATCH*157]            5024 B  per-block pair partials
// total ~1.03 MB

__device__ __forceinline__ float waveRedF(float v) {
    #pragma unroll
    for (int o = 32; o; o >>= 1) v += __shfl_down(v, o, 64);
    return v;
}
__device__ __forceinline__ unsigned int waveRedU(unsigned int v) {
    #pragma unroll
    for (int o = 32; o; o >>= 1) v += __shfl_down(v, o, 64);
    return v;
}

__global__ void __launch_bounds__(BDIM)
oc_scan(const float* __restrict__ beta, const int* __restrict__ t_idx,
        unsigned long long* __restrict__ pkey,
        float* __restrict__ nsp, unsigned int* __restrict__ ncp, int N) {
    const int tid = threadIdx.x;
    const int b   = blockIdx.y;
    const int sub = blockIdx.x;
    const int bid = b * NSCB + sub;
    const int chunk = (N + NSCB - 1) / NSCB;
    const int n0 = sub * chunk;
    const int n1 = min(n0 + chunk, N);

    __shared__ unsigned long long skey[KOBJ];
    if (tid < KOBJ) skey[tid] = 0ull;
    __syncthreads();

    float ns = 0.f;
    unsigned int nc = 0u;
    for (int n = n0 + tid; n < n1; n += BDIM) {
        const float bc = fminf(fmaxf(beta[(size_t)b * N + n], 1e-6f), 1.0f - 1e-5f);
        const int t = t_idx[(size_t)b * N + n];
        const unsigned long long kk =
            ((unsigned long long)__float_as_uint(bc) << 32) |
            (unsigned long long)(~(unsigned int)n);          // ties -> smallest n
        atomicMax(&skey[t], kk);                              // LDS atomic
        if (t == 0) { ns += bc; nc++; }
    }
    __syncthreads();
    if (tid < KOBJ) pkey[(size_t)bid * KOBJ + tid] = skey[tid];

    ns = waveRedF(ns);
    nc = waveRedU(nc);
    __shared__ float s_ns[4];
    __shared__ unsigned int s_nc[4];
    if ((tid & 63) == 0) { s_ns[tid >> 6] = ns; s_nc[tid >> 6] = nc; }
    __syncthreads();
    if (tid == 0) {
        float a = 0.f; unsigned int c = 0u;
        #pragma unroll
        for (int w = 0; w < BDIM / 64; ++w) { a += s_ns[w]; c += s_nc[w]; }
        nsp[bid] = a; ncp[bid] = c;
    }
}

__global__ void __launch_bounds__(KOBJ)
oc_reduce(const float* __restrict__ cc,
          const unsigned long long* __restrict__ pkey,
          const float* __restrict__ nsp, const unsigned int* __restrict__ ncp,
          float4* __restrict__ xaq, float* __restrict__ terms, int N) {
    const int b = blockIdx.x;
    const int k = threadIdx.x;          // 128 threads

    unsigned long long kv = 0ull;
    #pragma unroll 8
    for (int s = 0; s < NSCB; ++s) {
        const unsigned long long v = pkey[(size_t)(b * NSCB + s) * KOBJ + k];
        kv = v > kv ? v : kv;
    }
    const bool present = (kv != 0ull) && (k > 0);
    float x = 0.f, y = 0.f, qv = 0.f, lb = 0.f;
    unsigned int pc = 0u;
    if (kv != 0ull) {
        const unsigned int na = ~(unsigned int)(kv & 0xFFFFFFFFull);
        const float ba = __uint_as_float((unsigned int)(kv >> 32));
        const float2 xy = *(const float2*)&cc[((size_t)b * N + na) * 2];
        x = xy.x; y = xy.y;
        const float a = atanhf(ba / 1.002f);
        qv = a * a + QMIN;
        if (present) { lb = 1.f - ba; pc = 1u; }
    }
    xaq[(size_t)b * KOBJ + k] = make_float4(x, y, present ? qv : 0.f, 0.f);

    // noise partials: one per thread (NSCB == KOBJ == 128)
    float ns = nsp[b * NSCB + k];
    unsigned int nc = ncp[b * NSCB + k];

    lb = waveRedF(lb);  pc = waveRedU(pc);
    ns = waveRedF(ns);  nc = waveRedU(nc);
    __shared__ float s_lb[2], s_ns2[2];
    __shared__ unsigned int s_pc[2], s_nc2[2];
    const int wv = k >> 6;
    if ((k & 63) == 0) { s_lb[wv] = lb; s_pc[wv] = pc; s_ns2[wv] = ns; s_nc2[wv] = nc; }
    __syncthreads();
    if (k == 0) {
        const float L = s_lb[0] + s_lb[1];
        const unsigned int P = s_pc[0] + s_pc[1];
        const float A = s_ns2[0] + s_ns2[1];
        const unsigned int C = s_nc2[0] + s_nc2[1];
        terms[b] = L / (float)max(P, 1u) + SB * A / (float)max(C, 1u);
    }
}

__global__ void __launch_bounds__(PPB)
oc_pairs(const float* __restrict__ cc, const float* __restrict__ beta,
         const int* __restrict__ t_idx,
         const float4* __restrict__ xaq,
         float* __restrict__ pairp, int N) {
    const int tid = threadIdx.x;
    const int b   = blockIdx.y;
    const int sub = blockIdx.x;
    const int n   = sub * PPB + tid;

    __shared__ float2 sxy[KOBJ];
    __shared__ float  sqv[KOBJ];
    if (tid < KOBJ) {
        const float4 v = xaq[(size_t)b * KOBJ + tid];
        sxy[tid] = make_float2(v.x, v.y);
        sqv[tid] = v.z;
    }
    __syncthreads();

    float acc_tot = 0.f;
    if (n < N) {
        const float2 xy = *(const float2*)&cc[((size_t)b * N + n) * 2];
        const float bc = fminf(fmaxf(beta[(size_t)b * N + n], 1e-6f), 1.0f - 1e-5f);
        const int t = t_idx[(size_t)b * N + n];
        const float a = atanhf(bc / 1.002f);
        const float qn = a * a + QMIN;
        float acc = 0.f;
        #pragma unroll 8
        for (int k = 0; k < KOBJ; ++k) {
            const float dx = xy.x - sxy[k].x;
            const float dy = xy.y - sxy[k].y;
            const float d2 = fmaf(dy, dy, dx * dx);
            const float d = sqrtf(d2 + 1e-6f);
            acc = fmaf(fmaxf(0.f, 1.f - d), sqv[k], acc);    // repulsive for ALL k
        }
        // patch k==t: attractive d2 replaces the repulsive term
        const float2 st = sxy[t];
        const float dxt = xy.x - st.x;
        const float dyt = xy.y - st.y;
        const float d2t = fmaf(dyt, dyt, dxt * dxt);
        const float dt = sqrtf(d2t + 1e-6f);
        acc += sqv[t] * (d2t - fmaxf(0.f, 1.f - dt));
        acc_tot = acc * qn;
    }

    acc_tot = waveRedF(acc_tot);
    __shared__ float s_acc[PPB / 64];
    if ((tid & 63) == 0) s_acc[tid >> 6] = acc_tot;
    __syncthreads();
    if (tid == 0) {
        float s = 0.f;
        #pragma unroll
        for (int w = 0; w < PPB / 64; ++w) s += s_acc[w];
        pairp[(size_t)b * gridDim.x + sub] = s;
    }
}

__global__ void __launch_bounds__(512)
oc_final(const float* __restrict__ pairp, const float* __restrict__ terms,
         float* __restrict__ out, int N, int nppb) {
    const int tid = threadIdx.x;
    const int total = BATCH * nppb;
    float p = 0.f;
    for (int i = tid; i < total; i += 512) p += pairp[i];
    p = waveRedF(p);
    __shared__ float s_p[8];
    if ((tid & 63) == 0) s_p[tid >> 6] = p;
    __syncthreads();
    if (tid == 0) {
        float P = 0.f;
        #pragma unroll
        for (int w = 0; w < 8; ++w) P += s_p[w];
        float L = 0.f;
        #pragma unroll
        for (int bb = 0; bb < BATCH; ++bb) L += terms[bb];
        out[0] = (P / (float)N + L) / (float)BATCH;
    }
}

extern "C" void kernel_launch(void* const* d_in, const int* in_sizes, int n_in,
                              void* d_out, int out_size, void* d_ws, size_t ws_size,
                              hipStream_t stream) {
    const float* cc   = (const float*)d_in[0];   // (B,N,2) f32
    const float* beta = (const float*)d_in[1];   // (B,N)   f32
    const int*   tid  = (const int*)d_in[2];     // (B,N)   i32
    float* out = (float*)d_out;
    const int N = in_sizes[1] / BATCH;

    char* ws = (char*)d_ws;
    unsigned long long* pkey = (unsigned long long*)(ws + 0);
    float*        nsp   = (float*)(ws + 1048576);
    unsigned int* ncp   = (unsigned int*)(ws + 1052672);
    float4*       xaq   = (float4*)(ws + 1056768);
    float*        terms = (float*)(ws + 1073152);
    float*        pairp = (float*)(ws + 1073184);

    const int nppb = (N + PPB - 1) / PPB;        // pairs blocks per batch

    oc_scan  <<<dim3(NSCB, BATCH), BDIM, 0, stream>>>(beta, tid, pkey, nsp, ncp, N);
    oc_reduce<<<dim3(BATCH), KOBJ, 0, stream>>>(cc, pkey, nsp, ncp, xaq, terms, N);
    oc_pairs <<<dim3(nppb, BATCH), PPB, 0, stream>>>(cc, beta, tid, xaq, pairp, N);
    oc_final <<<dim3(1), 512, 0, stream>>>(pairp, terms, out, N, nppb);
}